// Round 4
// baseline (291.469 us; speedup 1.0000x reference)
//
#include <hip/hip_runtime.h>
#include <hip/hip_bf16.h>
#include <stdint.h>

// ---------- types ----------
typedef __attribute__((ext_vector_type(8))) __bf16 bf16x8;
typedef __attribute__((ext_vector_type(4))) float f32x4;

__device__ __forceinline__ unsigned short f2b(float f) {
    return __builtin_bit_cast(unsigned short, __float2bfloat16(f));
}

// async global -> LDS, 16B per lane (wave-uniform base + lane*16 dest order)
__device__ __forceinline__ void gload_lds16(const void* g, void* l) {
    __builtin_amdgcn_global_load_lds(
        (__attribute__((address_space(1))) void*)(uintptr_t)g,
        (__attribute__((address_space(3))) void*)l,
        16, 0, 0);
}

#define MFMA16(a, b, c) __builtin_amdgcn_mfma_f32_16x16x32_bf16((a), (b), (c), 0, 0, 0)

// ---------- constants ----------
// B=8192, S=39, A=4, D_IN=43 (pad 64), F=1024, E=8, C=10

// ---------- prep: SA pack + mixture weights ----------
__global__ void k_prep_sa(const float* __restrict__ state, const float* __restrict__ action,
                          const int* __restrict__ c, const float* __restrict__ Wte,
                          unsigned short* __restrict__ SA, float* __restrict__ wmix, int B) {
    int b = blockIdx.x * 256 + threadIdx.x;
    if (b >= B) return;
    unsigned short* row = SA + (size_t)b * 64;
#pragma unroll
    for (int i = 0; i < 39; ++i) row[i] = f2b(state[(size_t)b * 39 + i]);
#pragma unroll
    for (int i = 0; i < 4; ++i) row[39 + i] = f2b(action[(size_t)b * 4 + i]);
#pragma unroll
    for (int i = 43; i < 64; ++i) row[i] = 0;
    int ctx = c[b];
#pragma unroll
    for (int e = 0; e < 8; ++e) wmix[(size_t)b * 8 + e] = Wte[e * 10 + ctx];
}

// ---------- prep: W0 [E,43,1024] f32 -> W0T [E,1024,64] bf16 (n-major, k padded) ----------
__global__ void k_prep_w0t(const float* __restrict__ W0, unsigned short* __restrict__ W0T) {
    int idx = blockIdx.x * 256 + threadIdx.x;   // e*1024 + f
    int e = idx >> 10, f = idx & 1023;
    unsigned short* dst = W0T + (size_t)idx * 64;
#pragma unroll 1
    for (int k = 0; k < 43; ++k) dst[k] = f2b(W0[((size_t)e * 43 + k) * 1024 + f]);
#pragma unroll
    for (int k = 43; k < 64; ++k) dst[k] = 0;
}

// ---------- prep: W1 [E,1024,1024] f32 -> W1T [E,1024(n),1024(k)] bf16 ----------
__global__ void k_prep_w1t(const float* __restrict__ W1, unsigned short* __restrict__ W1T) {
    __shared__ float t[64][65];
    int k0 = blockIdx.x * 64, n0 = blockIdx.y * 64, e = blockIdx.z;
    int tid = threadIdx.x;
    int cl = tid & 63;      // n within tile
    int rg = tid >> 6;      // 0..3
    const float* src = W1 + ((size_t)e * 1024 + k0) * 1024 + n0;
#pragma unroll
    for (int i = 0; i < 16; ++i) {
        int kr = rg * 16 + i;
        t[kr][cl] = src[(size_t)kr * 1024 + cl];
    }
    __syncthreads();
    int nl = tid >> 2, kg = tid & 3;
    unsigned short* dst = W1T + ((size_t)e * 1024 + n0 + nl) * 1024 + k0 + kg * 16;
#pragma unroll
    for (int j = 0; j < 16; ++j) dst[j] = f2b(t[kg * 16 + j][nl]);
}

// ---------- layer 0: H0[e] = relu(SA @ W0T[e]^T + b0[e]), bf16 out ----------
__global__ __launch_bounds__(256, 2)
void k_layer0(const unsigned short* __restrict__ SA,   // [B,64]
              const unsigned short* __restrict__ W0T,  // [E,1024,64]
              const float* __restrict__ b0,            // [E,1024]
              unsigned short* __restrict__ H0,         // [E,Bc,1024]
              int Bc, int row0) {
    __shared__ unsigned short As[128 * 64];
    __shared__ unsigned short Bs[128 * 64];
    int bm = blockIdx.x, bn = blockIdx.y, e = blockIdx.z;
    int tid = threadIdx.x, lane = tid & 63;
    int wv = tid >> 6, wr = wv >> 1, wc = wv & 1;
    int l15 = lane & 15, kg = lane >> 4;

    const char* Ag = (const char*)(SA + (size_t)(row0 + bm * 128) * 64);
    const char* Bg = (const char*)(W0T + ((size_t)e * 1024 + bn * 128) * 64);
#pragma unroll
    for (int it = 0; it < 4; ++it) {
        int off = tid * 16 + it * 4096;   // both tiles are fully contiguous 16KB
        gload_lds16(Ag + off, (char*)As + off);
        gload_lds16(Bg + off, (char*)Bs + off);
    }
    __syncthreads();

    f32x4 acc[4][4];
#pragma unroll
    for (int mi = 0; mi < 4; ++mi)
#pragma unroll
        for (int ni = 0; ni < 4; ++ni) acc[mi][ni] = (f32x4)0.0f;

#pragma unroll
    for (int ks = 0; ks < 2; ++ks) {
        bf16x8 af[4], bv[4];
#pragma unroll
        for (int mi = 0; mi < 4; ++mi)
            af[mi] = *(const bf16x8*)&As[(wr * 64 + mi * 16 + l15) * 64 + ks * 32 + kg * 8];
#pragma unroll
        for (int ni = 0; ni < 4; ++ni)
            bv[ni] = *(const bf16x8*)&Bs[(wc * 64 + ni * 16 + l15) * 64 + ks * 32 + kg * 8];
#pragma unroll
        for (int mi = 0; mi < 4; ++mi)
#pragma unroll
            for (int ni = 0; ni < 4; ++ni)
                acc[mi][ni] = MFMA16(af[mi], bv[ni], acc[mi][ni]);
    }

    float b0v[4];
#pragma unroll
    for (int ni = 0; ni < 4; ++ni)
        b0v[ni] = b0[e * 1024 + bn * 128 + wc * 64 + ni * 16 + l15];
#pragma unroll
    for (int mi = 0; mi < 4; ++mi)
#pragma unroll
        for (int ni = 0; ni < 4; ++ni)
#pragma unroll
            for (int j = 0; j < 4; ++j) {
                int rloc = bm * 128 + wr * 64 + mi * 16 + kg * 4 + j;
                int col = bn * 128 + wc * 64 + ni * 16 + l15;
                float h = fmaxf(acc[mi][ni][j] + b0v[ni], 0.0f);
                H0[((size_t)e * Bc + rloc) * 1024 + col] = f2b(h);
            }
}

// ---------- layer 1 + mixing, 4-phase interleaved 256x128 tile ----------
// mixed = relu(sum_e w[b,e]*relu(H0[e] @ W1T[e]^T + b1[e]))
// 512 threads = 8 waves (2M x 4N), per-wave 128x32. BK=64, double-buffered LDS.
// Per K-tile: 4 phases; each phase = {gated barrier -> ds_read m-quadrant ->
// lgkmcnt(0)+sched_barrier -> setprio(1) 8xMFMA setprio(0) -> s_barrier}.
// Staging split: G0={B0,B1,A0,A2} at P0, G1={A1,A3} at P2, each vmcnt(6)-gated
// (FIFO: P0 queue [G0(t):4][G1(t):2][new:4] -> vmcnt(6) drains exactly G0(t);
//        P2 queue [G1(t):2][G0(t+1):4][new:2] -> vmcnt(6) drains G1(t)).
// Each phase drains lgkm before MFMA, so P3's trailing barrier makes
// next-iteration buffer reuse race-free.
__global__ __launch_bounds__(512, 2)
void k_layer1_mix(const unsigned short* __restrict__ H0,   // [E,Bc,1024]
                  const unsigned short* __restrict__ W1T,  // [E,1024(n),1024(k)]
                  const float* __restrict__ b1,            // [E,1024]
                  const float* __restrict__ wmix,          // [B,8] (global rows)
                  float* __restrict__ mixed,               // [Bc,1024]
                  int Bc, int row0) {
    __shared__ unsigned short As[2][256 * 64];   // 2 x 32 KB
    __shared__ unsigned short Bs[2][128 * 64];   // 2 x 16 KB
    __shared__ float wmixLds[256 * 8];           // 8 KB
    __shared__ float b1Lds[8 * 128];             // 4 KB

    int nwg = (Bc / 256) * 8;
    int wg = blockIdx.x;
    int cpx = nwg >> 3;                           // nwg % 8 == 0 (8 bn tiles)
    int swz = (wg & 7) * cpx + (wg >> 3);         // bijective XCD chunking
    int bm = swz >> 3, bn = swz & 7;

    int tid = threadIdx.x, lane = tid & 63;
    int wv = tid >> 6;
    int wr = wv >> 2, wc = wv & 3;                // 2M x 4N wave grid
    int l15 = lane & 15, kg = lane >> 4;
    int kg16 = kg * 16;
    int xsw = (l15 & 7) << 4;

    // ---- staging maps: 16B/lane; A = 4 issues (32KB), B = 2 issues (16KB)
    int tid16 = tid * 16;
    int aSrc[4], aDst[4], bSrc[2], bDst[2];
#pragma unroll
    for (int i = 0; i < 4; ++i) {
        int flat = tid16 + i * 8192;
        int row = flat >> 7, colb = flat & 127;
        aDst[i] = flat;
        aSrc[i] = row * 2048 + (colb ^ ((row & 7) << 4));   // inverse-swizzled source
    }
#pragma unroll
    for (int i = 0; i < 2; ++i) {
        int flat = tid16 + i * 8192;
        int row = flat >> 7, colb = flat & 127;
        bDst[i] = flat;
        bSrc[i] = row * 2048 + (colb ^ ((row & 7) << 4));
    }

    const char* h0base = (const char*)H0 + (size_t)(bm * 256) * 2048;
    const char* w1base = (const char*)W1T + (size_t)(bn * 128) * 2048;
    size_t eAstride = (size_t)Bc * 2048;

    // ---- fragment read offsets (swizzled reads; row&7 == l15&7 here)
    int aOff[8], bOff[2];
#pragma unroll
    for (int m = 0; m < 8; ++m) aOff[m] = (wr * 128 + m * 16 + l15) * 128;
#pragma unroll
    for (int n = 0; n < 2; ++n) bOff[n] = (wc * 32 + n * 16 + l15) * 128;

    // ---- preload wmix + b1 into LDS (keeps the K-loop vmcnt-silent)
    for (int idx = tid; idx < 2048; idx += 512) {
        int r = idx >> 3, e = idx & 7;
        wmixLds[idx] = wmix[(size_t)(row0 + bm * 256 + r) * 8 + e];
    }
    for (int idx = tid; idx < 1024; idx += 512)
        b1Lds[idx] = b1[(idx >> 7) * 1024 + bn * 128 + (idx & 127)];
    __syncthreads();   // full drain before pipeline starts

    f32x4 acc[8][2], mix[8][2];
#pragma unroll
    for (int m = 0; m < 8; ++m)
#pragma unroll
        for (int n = 0; n < 2; ++n) { acc[m][n] = (f32x4)0.0f; mix[m][n] = (f32x4)0.0f; }

    const int NT = 128;   // 8 experts * 16 K-tiles

    auto STAGE_G0 = [&](int tt) {   // B both halves + A row-groups 0,2 (rows 0-63,128-191)
        int e = tt >> 4;
        int k0b = (tt & 15) << 7;
        const char* Ab = h0base + (size_t)e * eAstride + k0b;
        const char* Bb = w1base + (size_t)e * (1024 * 2048) + k0b;
        char* Ad = (char*)As[tt & 1];
        char* Bd = (char*)Bs[tt & 1];
        gload_lds16(Bb + bSrc[0], Bd + bDst[0]);
        gload_lds16(Bb + bSrc[1], Bd + bDst[1]);
        gload_lds16(Ab + aSrc[0], Ad + aDst[0]);
        gload_lds16(Ab + aSrc[2], Ad + aDst[2]);
    };
    auto STAGE_G1 = [&](int tt) {   // A row-groups 1,3 (rows 64-127,192-255)
        int e = tt >> 4;
        int k0b = (tt & 15) << 7;
        const char* Ab = h0base + (size_t)e * eAstride + k0b;
        char* Ad = (char*)As[tt & 1];
        gload_lds16(Ab + aSrc[1], Ad + aDst[1]);
        gload_lds16(Ab + aSrc[3], Ad + aDst[3]);
    };

#define KB0 ((0 * 64 + kg16) ^ xsw)
#define KB1 ((1 * 64 + kg16) ^ xsw)

#define PHASE(M0, M1)                                                       \
    {                                                                       \
        bf16x8 a00 = *(const bf16x8*)(Ab + aOff[M0] + KB0);                 \
        bf16x8 a01 = *(const bf16x8*)(Ab + aOff[M0] + KB1);                 \
        bf16x8 a10 = *(const bf16x8*)(Ab + aOff[M1] + KB0);                 \
        bf16x8 a11 = *(const bf16x8*)(Ab + aOff[M1] + KB1);                 \
        asm volatile("s_waitcnt lgkmcnt(0)" ::: "memory");                  \
        __builtin_amdgcn_sched_barrier(0);                                  \
        __builtin_amdgcn_s_setprio(1);                                      \
        acc[M0][0] = MFMA16(a00, bf00, acc[M0][0]);                         \
        acc[M0][1] = MFMA16(a00, bf10, acc[M0][1]);                         \
        acc[M1][0] = MFMA16(a10, bf00, acc[M1][0]);                         \
        acc[M1][1] = MFMA16(a10, bf10, acc[M1][1]);                         \
        acc[M0][0] = MFMA16(a01, bf01, acc[M0][0]);                         \
        acc[M0][1] = MFMA16(a01, bf11, acc[M0][1]);                         \
        acc[M1][0] = MFMA16(a11, bf01, acc[M1][0]);                         \
        acc[M1][1] = MFMA16(a11, bf11, acc[M1][1]);                         \
        __builtin_amdgcn_s_setprio(0);                                      \
        __builtin_amdgcn_sched_barrier(0);                                  \
        asm volatile("s_barrier" ::: "memory");                             \
    }

    // prologue: stage tile 0 (G0 first, then G1 — FIFO order matters)
    STAGE_G0(0);
    STAGE_G1(0);

#pragma unroll 1
    for (int t = 0; t < NT; ++t) {
        const char* Ab = (const char*)As[t & 1];
        const char* Bb = (const char*)Bs[t & 1];

        // ---- P0: stage G0(t+1); gate on G0(t); B-frags + m{0,1}
        if (t + 1 < NT) {
            STAGE_G0(t + 1);
            asm volatile("s_waitcnt vmcnt(6)\n\ts_barrier" ::: "memory");
        } else {
            asm volatile("s_waitcnt vmcnt(2)\n\ts_barrier" ::: "memory");
        }
        __builtin_amdgcn_sched_barrier(0);
        bf16x8 bf00 = *(const bf16x8*)(Bb + bOff[0] + KB0);
        bf16x8 bf01 = *(const bf16x8*)(Bb + bOff[0] + KB1);
        bf16x8 bf10 = *(const bf16x8*)(Bb + bOff[1] + KB0);
        bf16x8 bf11 = *(const bf16x8*)(Bb + bOff[1] + KB1);
        PHASE(0, 1)

        // ---- P1: m{2,3}
        PHASE(2, 3)

        // ---- P2: stage G1(t+1); gate on G1(t); m{4,5}
        if (t + 1 < NT) {
            STAGE_G1(t + 1);
            asm volatile("s_waitcnt vmcnt(6)\n\ts_barrier" ::: "memory");
        } else {
            asm volatile("s_waitcnt vmcnt(0)\n\ts_barrier" ::: "memory");
        }
        __builtin_amdgcn_sched_barrier(0);
        PHASE(4, 5)

        // ---- P3: m{6,7}
        PHASE(6, 7)

        if ((t & 15) == 15) {
            // per-expert epilogue: bias + relu + weighted accumulate (LDS-const reads only)
            int e = t >> 4;
            float b1v[2];
#pragma unroll
            for (int n = 0; n < 2; ++n)
                b1v[n] = b1Lds[e * 128 + wc * 32 + n * 16 + l15];
#pragma unroll
            for (int m = 0; m < 8; ++m)
#pragma unroll
                for (int j = 0; j < 4; ++j) {
                    int lrow = wr * 128 + m * 16 + kg * 4 + j;
                    float w = wmixLds[lrow * 8 + e];
#pragma unroll
                    for (int n = 0; n < 2; ++n) {
                        float h = fmaxf(acc[m][n][j] + b1v[n], 0.0f);
                        mix[m][n][j] += w * h;
                        acc[m][n][j] = 0.0f;
                    }
                }
        }
    }
#undef PHASE
#undef KB0
#undef KB1

    // final relu + store
#pragma unroll
    for (int m = 0; m < 8; ++m)
#pragma unroll
        for (int n = 0; n < 2; ++n)
#pragma unroll
            for (int j = 0; j < 4; ++j) {
                int lrow = wr * 128 + m * 16 + kg * 4 + j;
                int col = bn * 128 + wc * 32 + n * 16 + l15;
                mixed[(size_t)(bm * 256 + lrow) * 1024 + col] = fmaxf(mix[m][n][j], 0.0f);
            }
}

// ---------- head: q[b] = mixed[b,:] . Wh[c[b],:] + bh[c[b]] ----------
__global__ void k_head(const float* __restrict__ mixed, const float* __restrict__ Wh,
                       const float* __restrict__ bh, const int* __restrict__ c,
                       float* __restrict__ q, int Bc, int row0) {
    int row = blockIdx.x * 4 + (threadIdx.x >> 6);
    int lane = threadIdx.x & 63;
    if (row >= Bc) return;
    int grow = row0 + row;
    int ctx = c[grow];
    const float4* m4 = (const float4*)(mixed + (size_t)row * 1024);
    const float4* w4 = (const float4*)(Wh + (size_t)ctx * 1024);
    float s = 0.0f;
#pragma unroll
    for (int i = 0; i < 4; ++i) {
        float4 a = m4[lane + i * 64];
        float4 b = w4[lane + i * 64];
        s += a.x * b.x + a.y * b.y + a.z * b.z + a.w * b.w;
    }
#pragma unroll
    for (int off = 32; off > 0; off >>= 1) s += __shfl_down(s, off);
    if (lane == 0) q[grow] = s + bh[ctx];
}

// ---------- host ----------
extern "C" void kernel_launch(void* const* d_in, const int* in_sizes, int n_in,
                              void* d_out, int out_size, void* d_ws, size_t ws_size,
                              hipStream_t stream) {
    const float* state  = (const float*)d_in[0];
    const float* action = (const float*)d_in[1];
    const int*   c      = (const int*)d_in[2];
    const float* W0     = (const float*)d_in[3];
    const float* b0     = (const float*)d_in[4];
    const float* W1     = (const float*)d_in[5];
    const float* b1     = (const float*)d_in[6];
    const float* Wte    = (const float*)d_in[7];
    const float* Wh     = (const float*)d_in[8];
    const float* bh     = (const float*)d_in[9];
    float* q = (float*)d_out;
    int B = in_sizes[2];   // c has B elements

    // workspace layout
    char* p = (char*)d_ws;
    unsigned short* W1T = (unsigned short*)p; p += (size_t)8 * 1024 * 1024 * 2;  // 16 MB
    unsigned short* W0T = (unsigned short*)p; p += (size_t)8 * 1024 * 64 * 2;    // 1 MB
    unsigned short* SA  = (unsigned short*)p; p += (size_t)B * 64 * 2;
    float* wmix         = (float*)p;          p += (size_t)B * 8 * 4;
    size_t fixed = (size_t)(p - (char*)d_ws);

    int Bc = B;
    while (Bc > 256 && fixed + (size_t)Bc * (8 * 1024 * 2 + 1024 * 4) > ws_size) Bc >>= 1;

    unsigned short* H0 = (unsigned short*)p; p += (size_t)8 * Bc * 1024 * 2;
    float* mixed       = (float*)p;

    k_prep_sa<<<(B + 255) / 256, 256, 0, stream>>>(state, action, c, Wte, SA, wmix, B);
    k_prep_w0t<<<(8 * 1024) / 256, 256, 0, stream>>>(W0, W0T);
    k_prep_w1t<<<dim3(16, 16, 8), 256, 0, stream>>>(W1, W1T);

    for (int row0 = 0; row0 < B; row0 += Bc) {
        k_layer0<<<dim3(Bc / 128, 8, 8), 256, 0, stream>>>(SA, W0T, b0, H0, Bc, row0);
        k_layer1_mix<<<(Bc / 256) * 8, 512, 0, stream>>>(H0, W1T, b1, wmix, mixed, Bc, row0);
        k_head<<<(Bc + 3) / 4, 256, 0, stream>>>(mixed, Wh, bh, c, q, Bc, row0);
    }
}

// Round 5
// 213.964 us; speedup vs baseline: 1.3622x; 1.3622x over previous
//
#include <hip/hip_runtime.h>
#include <hip/hip_bf16.h>
#include <stdint.h>

// ---------- types ----------
typedef __attribute__((ext_vector_type(8))) __bf16 bf16x8;
typedef __attribute__((ext_vector_type(4))) float f32x4;

__device__ __forceinline__ unsigned short f2b(float f) {
    return __builtin_bit_cast(unsigned short, __float2bfloat16(f));
}

// async global -> LDS, 16B per lane (wave-uniform base + lane*16 dest order)
__device__ __forceinline__ void gload_lds16(const void* g, void* l) {
    __builtin_amdgcn_global_load_lds(
        (__attribute__((address_space(1))) void*)(uintptr_t)g,
        (__attribute__((address_space(3))) void*)l,
        16, 0, 0);
}

#define MFMA16(a, b, c) __builtin_amdgcn_mfma_f32_16x16x32_bf16((a), (b), (c), 0, 0, 0)

// ---------- constants ----------
// B=8192, S=39, A=4, D_IN=43 (pad 64), F=1024, E=8, C=10

// ---------- prep: SA pack + mixture weights ----------
__global__ void k_prep_sa(const float* __restrict__ state, const float* __restrict__ action,
                          const int* __restrict__ c, const float* __restrict__ Wte,
                          unsigned short* __restrict__ SA, float* __restrict__ wmix, int B) {
    int b = blockIdx.x * 256 + threadIdx.x;
    if (b >= B) return;
    unsigned short* row = SA + (size_t)b * 64;
#pragma unroll
    for (int i = 0; i < 39; ++i) row[i] = f2b(state[(size_t)b * 39 + i]);
#pragma unroll
    for (int i = 0; i < 4; ++i) row[39 + i] = f2b(action[(size_t)b * 4 + i]);
#pragma unroll
    for (int i = 43; i < 64; ++i) row[i] = 0;
    int ctx = c[b];
#pragma unroll
    for (int e = 0; e < 8; ++e) wmix[(size_t)b * 8 + e] = Wte[e * 10 + ctx];
}

// ---------- prep: W0 [E,43,1024] f32 -> W0T [E,1024,64] bf16 (n-major, k padded) ----------
__global__ void k_prep_w0t(const float* __restrict__ W0, unsigned short* __restrict__ W0T) {
    int idx = blockIdx.x * 256 + threadIdx.x;   // e*1024 + f
    int e = idx >> 10, f = idx & 1023;
    unsigned short* dst = W0T + (size_t)idx * 64;
#pragma unroll 1
    for (int k = 0; k < 43; ++k) dst[k] = f2b(W0[((size_t)e * 43 + k) * 1024 + f]);
#pragma unroll
    for (int k = 43; k < 64; ++k) dst[k] = 0;
}

// ---------- prep: W1 [E,1024,1024] f32 -> W1T [E,1024(n),1024(k)] bf16 ----------
__global__ void k_prep_w1t(const float* __restrict__ W1, unsigned short* __restrict__ W1T) {
    __shared__ float t[64][65];
    int k0 = blockIdx.x * 64, n0 = blockIdx.y * 64, e = blockIdx.z;
    int tid = threadIdx.x;
    int cl = tid & 63;      // n within tile
    int rg = tid >> 6;      // 0..3
    const float* src = W1 + ((size_t)e * 1024 + k0) * 1024 + n0;
#pragma unroll
    for (int i = 0; i < 16; ++i) {
        int kr = rg * 16 + i;
        t[kr][cl] = src[(size_t)kr * 1024 + cl];
    }
    __syncthreads();
    int nl = tid >> 2, kg = tid & 3;
    unsigned short* dst = W1T + ((size_t)e * 1024 + n0 + nl) * 1024 + k0 + kg * 16;
#pragma unroll
    for (int j = 0; j < 16; ++j) dst[j] = f2b(t[kg * 16 + j][nl]);
}

// ---------- layer 0: H0[e] = relu(SA @ W0T[e]^T + b0[e]), bf16 out ----------
__global__ __launch_bounds__(256, 2)
void k_layer0(const unsigned short* __restrict__ SA,   // [B,64]
              const unsigned short* __restrict__ W0T,  // [E,1024,64]
              const float* __restrict__ b0,            // [E,1024]
              unsigned short* __restrict__ H0,         // [E,Bc,1024]
              int Bc, int row0) {
    __shared__ unsigned short As[128 * 64];
    __shared__ unsigned short Bs[128 * 64];
    int bm = blockIdx.x, bn = blockIdx.y, e = blockIdx.z;
    int tid = threadIdx.x, lane = tid & 63;
    int wv = tid >> 6, wr = wv >> 1, wc = wv & 1;
    int l15 = lane & 15, kg = lane >> 4;

    const char* Ag = (const char*)(SA + (size_t)(row0 + bm * 128) * 64);
    const char* Bg = (const char*)(W0T + ((size_t)e * 1024 + bn * 128) * 64);
#pragma unroll
    for (int it = 0; it < 4; ++it) {
        int off = tid * 16 + it * 4096;   // both tiles are fully contiguous 16KB
        gload_lds16(Ag + off, (char*)As + off);
        gload_lds16(Bg + off, (char*)Bs + off);
    }
    __syncthreads();

    f32x4 acc[4][4];
#pragma unroll
    for (int mi = 0; mi < 4; ++mi)
#pragma unroll
        for (int ni = 0; ni < 4; ++ni) acc[mi][ni] = (f32x4)0.0f;

#pragma unroll
    for (int ks = 0; ks < 2; ++ks) {
        bf16x8 af[4], bv[4];
#pragma unroll
        for (int mi = 0; mi < 4; ++mi)
            af[mi] = *(const bf16x8*)&As[(wr * 64 + mi * 16 + l15) * 64 + ks * 32 + kg * 8];
#pragma unroll
        for (int ni = 0; ni < 4; ++ni)
            bv[ni] = *(const bf16x8*)&Bs[(wc * 64 + ni * 16 + l15) * 64 + ks * 32 + kg * 8];
#pragma unroll
        for (int mi = 0; mi < 4; ++mi)
#pragma unroll
            for (int ni = 0; ni < 4; ++ni)
                acc[mi][ni] = MFMA16(af[mi], bv[ni], acc[mi][ni]);
    }

    float b0v[4];
#pragma unroll
    for (int ni = 0; ni < 4; ++ni)
        b0v[ni] = b0[e * 1024 + bn * 128 + wc * 64 + ni * 16 + l15];
#pragma unroll
    for (int mi = 0; mi < 4; ++mi)
#pragma unroll
        for (int ni = 0; ni < 4; ++ni)
#pragma unroll
            for (int j = 0; j < 4; ++j) {
                int rloc = bm * 128 + wr * 64 + mi * 16 + kg * 4 + j;
                int col = bn * 128 + wc * 64 + ni * 16 + l15;
                float h = fmaxf(acc[mi][ni][j] + b0v[ni], 0.0f);
                H0[((size_t)e * Bc + rloc) * 1024 + col] = f2b(h);
            }
}

// ---------- layer 1 + mixing, m201-style 2-phase-per-K-tile 256x128 tile ----------
// mixed = relu(sum_e w[b,e]*relu(H0[e] @ W1T[e]^T + b1[e]))
// 512 threads = 8 waves (2M x 4N), per-wave 128x32. BK=64, double-buffered LDS.
// Per K-tile: 2 phases of 16 MFMA. Each phase: {ds_reads issued || stage gloads
// issued} -> s_barrier (arrival skew hides LDS latency) -> lgkmcnt(0)+sched_barrier
// -> setprio(1) 16 MFMA setprio(0) -> TRAILING gated barrier with counted vmcnt.
// Stage split {B0,B1,A0,A2} (phase A) / {A1,A3} (phase B) gives FIFO gates:
//   after phase A: queue [A1ᵗ A3ᵗ | B0ᵗ⁺¹ B1ᵗ⁺¹ A0ᵗ⁺¹ A2ᵗ⁺¹] -> vmcnt(4)
//   after phase B: queue [B0ᵗ⁺¹ B1ᵗ⁺¹ A0ᵗ⁺¹ A2ᵗ⁺¹ A1ᵗ⁺¹ A3ᵗ⁺¹] -> vmcnt(2)
// (vmcnt+s_barrier pair: every wave passes its own gate, barrier certifies all.)
// Each phase's lgkmcnt(0) precedes its trailing barrier -> buffer reuse race-free.
__global__ __launch_bounds__(512, 2)
void k_layer1_mix(const unsigned short* __restrict__ H0,   // [E,Bc,1024]
                  const unsigned short* __restrict__ W1T,  // [E,1024(n),1024(k)]
                  const float* __restrict__ b1,            // [E,1024]
                  const float* __restrict__ wmix,          // [B,8] (global rows)
                  float* __restrict__ mixed,               // [Bc,1024]
                  int Bc, int row0) {
    __shared__ unsigned short As[2][256 * 64];   // 2 x 32 KB
    __shared__ unsigned short Bs[2][128 * 64];   // 2 x 16 KB
    __shared__ float wmixLds[256 * 8];           // 8 KB
    __shared__ float b1Lds[8 * 128];             // 4 KB

    int nbm = Bc / 256;
    int wg = blockIdx.x;
    // XCD-coherent mapping: all 8 bn-siblings of a bm share the same A-panel;
    // put them on ONE XCD (xcd = wg%8) so the panel flows through that L2 once.
    int bm, bn;
    if ((nbm & 7) == 0) {
        bm = (wg & 7) + ((wg >> 6) << 3);
        bn = (wg >> 3) & 7;
    } else {
        bm = wg >> 3;
        bn = wg & 7;
    }

    int tid = threadIdx.x, lane = tid & 63;
    int wv = tid >> 6;
    int wr = wv >> 2, wc = wv & 3;                // 2M x 4N wave grid
    int l15 = lane & 15, kg = lane >> 4;
    int kg16 = kg * 16;
    int xsw = (l15 & 7) << 4;

    // ---- staging maps: 16B/lane; A = 4 issues (32KB), B = 2 issues (16KB)
    int tid16 = tid * 16;
    int aSrc[4], aDst[4], bSrc[2], bDst[2];
#pragma unroll
    for (int i = 0; i < 4; ++i) {
        int flat = tid16 + i * 8192;
        int row = flat >> 7, colb = flat & 127;
        aDst[i] = flat;
        aSrc[i] = row * 2048 + (colb ^ ((row & 7) << 4));   // inverse-swizzled source
    }
#pragma unroll
    for (int i = 0; i < 2; ++i) {
        int flat = tid16 + i * 8192;
        int row = flat >> 7, colb = flat & 127;
        bDst[i] = flat;
        bSrc[i] = row * 2048 + (colb ^ ((row & 7) << 4));
    }

    const char* h0base = (const char*)H0 + (size_t)(bm * 256) * 2048;
    const char* w1base = (const char*)W1T + (size_t)(bn * 128) * 2048;
    size_t eAstride = (size_t)Bc * 2048;

    // ---- fragment read offsets (swizzled reads; row&7 == l15&7 here)
    int aOff[8], bOff[2];
#pragma unroll
    for (int m = 0; m < 8; ++m) aOff[m] = (wr * 128 + m * 16 + l15) * 128;
#pragma unroll
    for (int n = 0; n < 2; ++n) bOff[n] = (wc * 32 + n * 16 + l15) * 128;

    // ---- preload wmix + b1 into LDS (keeps the K-loop vmcnt-silent)
    for (int idx = tid; idx < 2048; idx += 512) {
        int r = idx >> 3, e = idx & 7;
        wmixLds[idx] = wmix[(size_t)(row0 + bm * 256 + r) * 8 + e];
    }
    for (int idx = tid; idx < 1024; idx += 512)
        b1Lds[idx] = b1[(idx >> 7) * 1024 + bn * 128 + (idx & 127)];
    __syncthreads();   // full drain (incl. vmcnt) before the pipeline starts

    f32x4 acc[8][2], mix[8][2];
#pragma unroll
    for (int m = 0; m < 8; ++m)
#pragma unroll
        for (int n = 0; n < 2; ++n) { acc[m][n] = (f32x4)0.0f; mix[m][n] = (f32x4)0.0f; }

    const int NT = 128;   // 8 experts * 16 K-tiles

    auto STAGE_PA = [&](int tt) {   // B (both) + A row-groups 0,2 (phase-A's rows)
        int e = tt >> 4;
        int k0b = (tt & 15) << 7;
        const char* Ab = h0base + (size_t)e * eAstride + k0b;
        const char* Bb = w1base + (size_t)e * (1024 * 2048) + k0b;
        char* Ad = (char*)As[tt & 1];
        char* Bd = (char*)Bs[tt & 1];
        gload_lds16(Bb + bSrc[0], Bd + bDst[0]);
        gload_lds16(Bb + bSrc[1], Bd + bDst[1]);
        gload_lds16(Ab + aSrc[0], Ad + aDst[0]);
        gload_lds16(Ab + aSrc[2], Ad + aDst[2]);
    };
    auto STAGE_PB = [&](int tt) {   // A row-groups 1,3 (phase-B's rows)
        int e = tt >> 4;
        int k0b = (tt & 15) << 7;
        const char* Ab = h0base + (size_t)e * eAstride + k0b;
        char* Ad = (char*)As[tt & 1];
        gload_lds16(Ab + aSrc[1], Ad + aDst[1]);
        gload_lds16(Ab + aSrc[3], Ad + aDst[3]);
    };

#define KB0 ((0 * 64 + kg16) ^ xsw)
#define KB1 ((1 * 64 + kg16) ^ xsw)

    // prologue: stage tile 0; gate its phase-A data (first 4 of 6 loads)
    STAGE_PA(0);
    STAGE_PB(0);
    asm volatile("s_waitcnt vmcnt(2)\n\ts_barrier" ::: "memory");

#pragma unroll 1
    for (int t = 0; t < NT; ++t) {
        const char* Ab = (const char*)As[t & 1];
        const char* Bb = (const char*)Bs[t & 1];

        // ================= PHASE A: m0-3 =================
        bf16x8 bfr[2][2];
#pragma unroll
        for (int n = 0; n < 2; ++n) {
            bfr[n][0] = *(const bf16x8*)(Bb + bOff[n] + KB0);
            bfr[n][1] = *(const bf16x8*)(Bb + bOff[n] + KB1);
        }
        bf16x8 af[4][2];
#pragma unroll
        for (int m = 0; m < 4; ++m) {
            af[m][0] = *(const bf16x8*)(Ab + aOff[m] + KB0);
            af[m][1] = *(const bf16x8*)(Ab + aOff[m] + KB1);
        }
        if (t + 1 < NT) STAGE_PA(t + 1);
        asm volatile("s_barrier" ::: "memory");           // reads in flight across sync
        asm volatile("s_waitcnt lgkmcnt(0)" ::: "memory");
        __builtin_amdgcn_sched_barrier(0);
        __builtin_amdgcn_s_setprio(1);
#pragma unroll
        for (int k = 0; k < 2; ++k)
#pragma unroll
            for (int m = 0; m < 4; ++m)
#pragma unroll
                for (int n = 0; n < 2; ++n)
                    acc[m][n] = MFMA16(af[m][k], bfr[n][k], acc[m][n]);
        __builtin_amdgcn_s_setprio(0);
        __builtin_amdgcn_sched_barrier(0);
        if (t + 1 < NT)
            asm volatile("s_waitcnt vmcnt(4)\n\ts_barrier" ::: "memory");  // A1ᵗ,A3ᵗ landed
        else
            asm volatile("s_waitcnt vmcnt(0)\n\ts_barrier" ::: "memory");

        // ================= PHASE B: m4-7 =================
        bf16x8 ag[4][2];
#pragma unroll
        for (int m = 0; m < 4; ++m) {
            ag[m][0] = *(const bf16x8*)(Ab + aOff[4 + m] + KB0);
            ag[m][1] = *(const bf16x8*)(Ab + aOff[4 + m] + KB1);
        }
        if (t + 1 < NT) STAGE_PB(t + 1);
        asm volatile("s_barrier" ::: "memory");
        asm volatile("s_waitcnt lgkmcnt(0)" ::: "memory");
        __builtin_amdgcn_sched_barrier(0);
        __builtin_amdgcn_s_setprio(1);
#pragma unroll
        for (int k = 0; k < 2; ++k)
#pragma unroll
            for (int m = 0; m < 4; ++m)
#pragma unroll
                for (int n = 0; n < 2; ++n)
                    acc[4 + m][n] = MFMA16(ag[m][k], bfr[n][k], acc[4 + m][n]);
        __builtin_amdgcn_s_setprio(0);
        __builtin_amdgcn_sched_barrier(0);
        if (t + 1 < NT)
            asm volatile("s_waitcnt vmcnt(2)\n\ts_barrier" ::: "memory");  // tile t+1 phase-A data landed
        else
            asm volatile("s_waitcnt vmcnt(0)\n\ts_barrier" ::: "memory");

        if ((t & 15) == 15) {
            // per-expert epilogue: bias + relu + weighted accumulate (LDS-const only)
            int e = t >> 4;
            float b1v[2];
#pragma unroll
            for (int n = 0; n < 2; ++n)
                b1v[n] = b1Lds[e * 128 + wc * 32 + n * 16 + l15];
#pragma unroll
            for (int m = 0; m < 8; ++m)
#pragma unroll
                for (int j = 0; j < 4; ++j) {
                    int lrow = wr * 128 + m * 16 + kg * 4 + j;
                    float w = wmixLds[lrow * 8 + e];
#pragma unroll
                    for (int n = 0; n < 2; ++n) {
                        float h = fmaxf(acc[m][n][j] + b1v[n], 0.0f);
                        mix[m][n][j] += w * h;
                        acc[m][n][j] = 0.0f;
                    }
                }
        }
    }
#undef KB0
#undef KB1

    // final relu + store
#pragma unroll
    for (int m = 0; m < 8; ++m)
#pragma unroll
        for (int n = 0; n < 2; ++n)
#pragma unroll
            for (int j = 0; j < 4; ++j) {
                int lrow = wr * 128 + m * 16 + kg * 4 + j;
                int col = bn * 128 + wc * 32 + n * 16 + l15;
                mixed[(size_t)(bm * 256 + lrow) * 1024 + col] = fmaxf(mix[m][n][j], 0.0f);
            }
}

// ---------- head: q[b] = mixed[b,:] . Wh[c[b],:] + bh[c[b]] ----------
__global__ void k_head(const float* __restrict__ mixed, const float* __restrict__ Wh,
                       const float* __restrict__ bh, const int* __restrict__ c,
                       float* __restrict__ q, int Bc, int row0) {
    int row = blockIdx.x * 4 + (threadIdx.x >> 6);
    int lane = threadIdx.x & 63;
    if (row >= Bc) return;
    int grow = row0 + row;
    int ctx = c[grow];
    const float4* m4 = (const float4*)(mixed + (size_t)row * 1024);
    const float4* w4 = (const float4*)(Wh + (size_t)ctx * 1024);
    float s = 0.0f;
#pragma unroll
    for (int i = 0; i < 4; ++i) {
        float4 a = m4[lane + i * 64];
        float4 b = w4[lane + i * 64];
        s += a.x * b.x + a.y * b.y + a.z * b.z + a.w * b.w;
    }
#pragma unroll
    for (int off = 32; off > 0; off >>= 1) s += __shfl_down(s, off);
    if (lane == 0) q[grow] = s + bh[ctx];
}

// ---------- host ----------
extern "C" void kernel_launch(void* const* d_in, const int* in_sizes, int n_in,
                              void* d_out, int out_size, void* d_ws, size_t ws_size,
                              hipStream_t stream) {
    const float* state  = (const float*)d_in[0];
    const float* action = (const float*)d_in[1];
    const int*   c      = (const int*)d_in[2];
    const float* W0     = (const float*)d_in[3];
    const float* b0     = (const float*)d_in[4];
    const float* W1     = (const float*)d_in[5];
    const float* b1     = (const float*)d_in[6];
    const float* Wte    = (const float*)d_in[7];
    const float* Wh     = (const float*)d_in[8];
    const float* bh     = (const float*)d_in[9];
    float* q = (float*)d_out;
    int B = in_sizes[2];   // c has B elements

    // workspace layout
    char* p = (char*)d_ws;
    unsigned short* W1T = (unsigned short*)p; p += (size_t)8 * 1024 * 1024 * 2;  // 16 MB
    unsigned short* W0T = (unsigned short*)p; p += (size_t)8 * 1024 * 64 * 2;    // 1 MB
    unsigned short* SA  = (unsigned short*)p; p += (size_t)B * 64 * 2;
    float* wmix         = (float*)p;          p += (size_t)B * 8 * 4;
    size_t fixed = (size_t)(p - (char*)d_ws);

    int Bc = B;
    while (Bc > 256 && fixed + (size_t)Bc * (8 * 1024 * 2 + 1024 * 4) > ws_size) Bc >>= 1;

    unsigned short* H0 = (unsigned short*)p; p += (size_t)8 * Bc * 1024 * 2;
    float* mixed       = (float*)p;

    k_prep_sa<<<(B + 255) / 256, 256, 0, stream>>>(state, action, c, Wte, SA, wmix, B);
    k_prep_w0t<<<(8 * 1024) / 256, 256, 0, stream>>>(W0, W0T);
    k_prep_w1t<<<dim3(16, 16, 8), 256, 0, stream>>>(W1, W1T);

    for (int row0 = 0; row0 < B; row0 += Bc) {
        k_layer0<<<dim3(Bc / 128, 8, 8), 256, 0, stream>>>(SA, W0T, b0, H0, Bc, row0);
        k_layer1_mix<<<(Bc / 256) * 8, 512, 0, stream>>>(H0, W1T, b1, wmix, mixed, Bc, row0);
        k_head<<<(Bc + 3) / 4, 256, 0, stream>>>(mixed, Wh, bh, c, q, Bc, row0);
    }
}

// Round 6
// 197.341 us; speedup vs baseline: 1.4770x; 1.0842x over previous
//
#include <hip/hip_runtime.h>
#include <hip/hip_bf16.h>
#include <stdint.h>

// ---------- types ----------
typedef __attribute__((ext_vector_type(8))) __bf16 bf16x8;
typedef __attribute__((ext_vector_type(4))) float f32x4;

__device__ __forceinline__ unsigned short f2b(float f) {
    return __builtin_bit_cast(unsigned short, __float2bfloat16(f));
}

// async global -> LDS, 16B per lane (wave-uniform base + lane*16 dest order)
__device__ __forceinline__ void gload_lds16(const void* g, void* l) {
    __builtin_amdgcn_global_load_lds(
        (__attribute__((address_space(1))) void*)(uintptr_t)g,
        (__attribute__((address_space(3))) void*)l,
        16, 0, 0);
}

#define MFMA16(a, b, c) __builtin_amdgcn_mfma_f32_16x16x32_bf16((a), (b), (c), 0, 0, 0)

// ---------- constants ----------
// B=8192, S=39, A=4, D_IN=43 (pad 64), F=1024, E=8, C=10

// ---------- prep: SA pack + mixture weights ----------
__global__ void k_prep_sa(const float* __restrict__ state, const float* __restrict__ action,
                          const int* __restrict__ c, const float* __restrict__ Wte,
                          unsigned short* __restrict__ SA, float* __restrict__ wmix, int B) {
    int b = blockIdx.x * 256 + threadIdx.x;
    if (b >= B) return;
    unsigned short* row = SA + (size_t)b * 64;
#pragma unroll
    for (int i = 0; i < 39; ++i) row[i] = f2b(state[(size_t)b * 39 + i]);
#pragma unroll
    for (int i = 0; i < 4; ++i) row[39 + i] = f2b(action[(size_t)b * 4 + i]);
#pragma unroll
    for (int i = 43; i < 64; ++i) row[i] = 0;
    int ctx = c[b];
#pragma unroll
    for (int e = 0; e < 8; ++e) wmix[(size_t)b * 8 + e] = Wte[e * 10 + ctx];
}

// ---------- prep: W0 [E,43,1024] f32 -> W0T [E,1024,64] bf16 (n-major, k padded) ----------
__global__ void k_prep_w0t(const float* __restrict__ W0, unsigned short* __restrict__ W0T) {
    int idx = blockIdx.x * 256 + threadIdx.x;   // e*1024 + f
    int e = idx >> 10, f = idx & 1023;
    unsigned short* dst = W0T + (size_t)idx * 64;
#pragma unroll 1
    for (int k = 0; k < 43; ++k) dst[k] = f2b(W0[((size_t)e * 43 + k) * 1024 + f]);
#pragma unroll
    for (int k = 43; k < 64; ++k) dst[k] = 0;
}

// ---------- prep: W1 [E,1024,1024] f32 -> W1T [E,1024(n),1024(k)] bf16 ----------
__global__ void k_prep_w1t(const float* __restrict__ W1, unsigned short* __restrict__ W1T) {
    __shared__ float t[64][65];
    int k0 = blockIdx.x * 64, n0 = blockIdx.y * 64, e = blockIdx.z;
    int tid = threadIdx.x;
    int cl = tid & 63;      // n within tile
    int rg = tid >> 6;      // 0..3
    const float* src = W1 + ((size_t)e * 1024 + k0) * 1024 + n0;
#pragma unroll
    for (int i = 0; i < 16; ++i) {
        int kr = rg * 16 + i;
        t[kr][cl] = src[(size_t)kr * 1024 + cl];
    }
    __syncthreads();
    int nl = tid >> 2, kg = tid & 3;
    unsigned short* dst = W1T + ((size_t)e * 1024 + n0 + nl) * 1024 + k0 + kg * 16;
#pragma unroll
    for (int j = 0; j < 16; ++j) dst[j] = f2b(t[kg * 16 + j][nl]);
}

// ---------- layer 0: H0[e] = relu(SA @ W0T[e]^T + b0[e]), bf16 out ----------
__global__ __launch_bounds__(256, 2)
void k_layer0(const unsigned short* __restrict__ SA,   // [B,64]
              const unsigned short* __restrict__ W0T,  // [E,1024,64]
              const float* __restrict__ b0,            // [E,1024]
              unsigned short* __restrict__ H0,         // [E,Bc,1024]
              int Bc, int row0) {
    __shared__ unsigned short As[128 * 64];
    __shared__ unsigned short Bs[128 * 64];
    int bm = blockIdx.x, bn = blockIdx.y, e = blockIdx.z;
    int tid = threadIdx.x, lane = tid & 63;
    int wv = tid >> 6, wr = wv >> 1, wc = wv & 1;
    int l15 = lane & 15, kg = lane >> 4;

    const char* Ag = (const char*)(SA + (size_t)(row0 + bm * 128) * 64);
    const char* Bg = (const char*)(W0T + ((size_t)e * 1024 + bn * 128) * 64);
#pragma unroll
    for (int it = 0; it < 4; ++it) {
        int off = tid * 16 + it * 4096;   // both tiles are fully contiguous 16KB
        gload_lds16(Ag + off, (char*)As + off);
        gload_lds16(Bg + off, (char*)Bs + off);
    }
    __syncthreads();

    f32x4 acc[4][4];
#pragma unroll
    for (int mi = 0; mi < 4; ++mi)
#pragma unroll
        for (int ni = 0; ni < 4; ++ni) acc[mi][ni] = (f32x4)0.0f;

#pragma unroll
    for (int ks = 0; ks < 2; ++ks) {
        bf16x8 af[4], bv[4];
#pragma unroll
        for (int mi = 0; mi < 4; ++mi)
            af[mi] = *(const bf16x8*)&As[(wr * 64 + mi * 16 + l15) * 64 + ks * 32 + kg * 8];
#pragma unroll
        for (int ni = 0; ni < 4; ++ni)
            bv[ni] = *(const bf16x8*)&Bs[(wc * 64 + ni * 16 + l15) * 64 + ks * 32 + kg * 8];
#pragma unroll
        for (int mi = 0; mi < 4; ++mi)
#pragma unroll
            for (int ni = 0; ni < 4; ++ni)
                acc[mi][ni] = MFMA16(af[mi], bv[ni], acc[mi][ni]);
    }

    float b0v[4];
#pragma unroll
    for (int ni = 0; ni < 4; ++ni)
        b0v[ni] = b0[e * 1024 + bn * 128 + wc * 64 + ni * 16 + l15];
#pragma unroll
    for (int mi = 0; mi < 4; ++mi)
#pragma unroll
        for (int ni = 0; ni < 4; ++ni)
#pragma unroll
            for (int j = 0; j < 4; ++j) {
                int rloc = bm * 128 + wr * 64 + mi * 16 + kg * 4 + j;
                int col = bn * 128 + wc * 64 + ni * 16 + l15;
                float h = fmaxf(acc[mi][ni][j] + b0v[ni], 0.0f);
                H0[((size_t)e * Bc + rloc) * 1024 + col] = f2b(h);
            }
}

// ---------- layer 1 + mixing: 128x128 tile, 2-phase pipeline, 2 blocks/CU ----------
// mixed = relu(sum_e w[b,e]*relu(H0[e] @ W1T[e]^T + b1[e]))
// 256 threads = 4 waves (2M x 2N), per-wave 64x64. BK=64, double-buffered LDS (72KB
// total -> 2 blocks/CU; grid 512 = 2/CU). Inter-block overlap absorbs the vmcnt /
// barrier stalls that serialized the 1-block/CU version (m114 mechanism).
// Per K-tile: 2 phases of 16 MFMA; reads+stages issued BEFORE the barrier.
// Stage split {B0..B3,A0,A2} (PA) / {A1,A3} (PB); FIFO gates:
//   after PA: queue [A1ᵗ A3ᵗ | 6 of t+1] -> vmcnt(6) certifies PB's data
//   after PB: queue [6 PA(t+1) | 2 PB(t+1)] -> vmcnt(2) certifies PA(t+1)
// Each phase drains lgkmcnt(0) before its trailing barrier -> buffer reuse safe.
__global__ __launch_bounds__(256, 2)
void k_layer1_mix(const unsigned short* __restrict__ H0,   // [E,Bc,1024]
                  const unsigned short* __restrict__ W1T,  // [E,1024(n),1024(k)]
                  const float* __restrict__ b1,            // [E,1024]
                  const float* __restrict__ wmix,          // [B,8] (global rows)
                  float* __restrict__ mixed,               // [Bc,1024]
                  int Bc, int row0) {
    __shared__ unsigned short As[2][128 * 64];   // 2 x 16 KB
    __shared__ unsigned short Bs[2][128 * 64];   // 2 x 16 KB
    __shared__ float wmixLds[128 * 8];           // 4 KB
    __shared__ float b1Lds[8 * 128];             // 4 KB

    int nbm = Bc / 128;
    int wg = blockIdx.x;
    // XCD-coherent mapping (assumes XCD = wg % 8): the 8 bn-siblings of a bm get
    // consecutive slots on ONE XCD, so the shared A-panel flows through its L2 once.
    int bm, bn;
    if ((nbm & 7) == 0) {
        int xcd = wg & 7, j = wg >> 3;        // j in [0, nbm)
        bm = xcd + ((j >> 3) << 3);
        bn = j & 7;
    } else {
        bm = wg >> 3;
        bn = wg & 7;
    }

    int tid = threadIdx.x, lane = tid & 63;
    int wv = tid >> 6;
    int wr = wv >> 1, wc = wv & 1;                // 2M x 2N wave grid
    int l15 = lane & 15, kg = lane >> 4;
    int kg16 = kg * 16;
    int xsw = (l15 & 7) << 4;

    // ---- staging maps: 16B/lane; A and B each 4 issues of 4KB (rows of 128B)
    int tid16 = tid * 16;
    int sSrc[4], sDst[4];
#pragma unroll
    for (int i = 0; i < 4; ++i) {
        int flat = tid16 + i * 4096;
        int row = flat >> 7, colb = flat & 127;
        sDst[i] = flat;
        sSrc[i] = row * 2048 + (colb ^ ((row & 7) << 4));   // inverse-swizzled source
    }

    const char* h0base = (const char*)H0 + (size_t)(bm * 128) * 2048;
    const char* w1base = (const char*)W1T + (size_t)(bn * 128) * 2048;
    size_t eAstride = (size_t)Bc * 2048;

    // ---- fragment read offsets (swizzled; row&7 == l15&7 here)
    int aOff[4], bOff[4];
#pragma unroll
    for (int m = 0; m < 4; ++m) aOff[m] = (wr * 64 + m * 16 + l15) * 128;
#pragma unroll
    for (int n = 0; n < 4; ++n) bOff[n] = (wc * 64 + n * 16 + l15) * 128;

    // ---- preload wmix + b1 into LDS (keeps the K-loop vmcnt-silent)
    for (int idx = tid; idx < 1024; idx += 256) {
        int r = idx >> 3, e = idx & 7;
        wmixLds[idx] = wmix[(size_t)(row0 + bm * 128 + r) * 8 + e];
    }
    for (int idx = tid; idx < 1024; idx += 256)
        b1Lds[idx] = b1[(idx >> 7) * 1024 + bn * 128 + (idx & 127)];
    __syncthreads();   // full drain before the pipeline starts

    f32x4 acc[4][4], mix[4][4];
#pragma unroll
    for (int m = 0; m < 4; ++m)
#pragma unroll
        for (int n = 0; n < 4; ++n) { acc[m][n] = (f32x4)0.0f; mix[m][n] = (f32x4)0.0f; }

    const int NT = 128;   // 8 experts * 16 K-tiles

    auto STAGE_PA = [&](int tt) {   // B full tile + A row-groups 0,2 (phase-A rows)
        int e = tt >> 4;
        int k0b = (tt & 15) << 7;
        const char* Ab = h0base + (size_t)e * eAstride + k0b;
        const char* Bb = w1base + (size_t)e * (1024 * 2048) + k0b;
        char* Ad = (char*)As[tt & 1];
        char* Bd = (char*)Bs[tt & 1];
        gload_lds16(Bb + sSrc[0], Bd + sDst[0]);
        gload_lds16(Bb + sSrc[1], Bd + sDst[1]);
        gload_lds16(Bb + sSrc[2], Bd + sDst[2]);
        gload_lds16(Bb + sSrc[3], Bd + sDst[3]);
        gload_lds16(Ab + sSrc[0], Ad + sDst[0]);
        gload_lds16(Ab + sSrc[2], Ad + sDst[2]);
    };
    auto STAGE_PB = [&](int tt) {   // A row-groups 1,3 (phase-B rows)
        int e = tt >> 4;
        int k0b = (tt & 15) << 7;
        const char* Ab = h0base + (size_t)e * eAstride + k0b;
        char* Ad = (char*)As[tt & 1];
        gload_lds16(Ab + sSrc[1], Ad + sDst[1]);
        gload_lds16(Ab + sSrc[3], Ad + sDst[3]);
    };

#define KB0 ((kg16) ^ xsw)
#define KB1 ((64 + kg16) ^ xsw)

    // prologue: stage tile 0; gate phase-A's 6 loads (2 may still fly)
    STAGE_PA(0);
    STAGE_PB(0);
    asm volatile("s_waitcnt vmcnt(2)\n\ts_barrier" ::: "memory");

#pragma unroll 1
    for (int t = 0; t < NT; ++t) {
        const char* Ab = (const char*)As[t & 1];
        const char* Bb = (const char*)Bs[t & 1];

        // ================= PHASE A: m0,m1 (x 4n) =================
        bf16x8 bfr[4][2];
#pragma unroll
        for (int n = 0; n < 4; ++n) {
            bfr[n][0] = *(const bf16x8*)(Bb + bOff[n] + KB0);
            bfr[n][1] = *(const bf16x8*)(Bb + bOff[n] + KB1);
        }
        bf16x8 af[2][2];
#pragma unroll
        for (int m = 0; m < 2; ++m) {
            af[m][0] = *(const bf16x8*)(Ab + aOff[m] + KB0);
            af[m][1] = *(const bf16x8*)(Ab + aOff[m] + KB1);
        }
        if (t + 1 < NT) STAGE_PA(t + 1);
        asm volatile("s_barrier" ::: "memory");           // reads stay in flight across sync
        asm volatile("s_waitcnt lgkmcnt(0)" ::: "memory");
        __builtin_amdgcn_sched_barrier(0);
        __builtin_amdgcn_s_setprio(1);
#pragma unroll
        for (int k = 0; k < 2; ++k)
#pragma unroll
            for (int m = 0; m < 2; ++m)
#pragma unroll
                for (int n = 0; n < 4; ++n)
                    acc[m][n] = MFMA16(af[m][k], bfr[n][k], acc[m][n]);
        __builtin_amdgcn_s_setprio(0);
        __builtin_amdgcn_sched_barrier(0);
        if (t + 1 < NT)
            asm volatile("s_waitcnt vmcnt(6)\n\ts_barrier" ::: "memory");  // A1ᵗ,A3ᵗ landed
        else
            asm volatile("s_waitcnt vmcnt(0)\n\ts_barrier" ::: "memory");

        // ================= PHASE B: m2,m3 (x 4n) =================
        bf16x8 ag[2][2];
#pragma unroll
        for (int m = 0; m < 2; ++m) {
            ag[m][0] = *(const bf16x8*)(Ab + aOff[2 + m] + KB0);
            ag[m][1] = *(const bf16x8*)(Ab + aOff[2 + m] + KB1);
        }
        if (t + 1 < NT) STAGE_PB(t + 1);
        asm volatile("s_barrier" ::: "memory");
        asm volatile("s_waitcnt lgkmcnt(0)" ::: "memory");
        __builtin_amdgcn_sched_barrier(0);
        __builtin_amdgcn_s_setprio(1);
#pragma unroll
        for (int k = 0; k < 2; ++k)
#pragma unroll
            for (int m = 0; m < 2; ++m)
#pragma unroll
                for (int n = 0; n < 4; ++n)
                    acc[2 + m][n] = MFMA16(ag[m][k], bfr[n][k], acc[2 + m][n]);
        __builtin_amdgcn_s_setprio(0);
        __builtin_amdgcn_sched_barrier(0);
        if (t + 1 < NT)
            asm volatile("s_waitcnt vmcnt(2)\n\ts_barrier" ::: "memory");  // PA(t+1) landed
        else
            asm volatile("s_waitcnt vmcnt(0)\n\ts_barrier" ::: "memory");

        if ((t & 15) == 15) {
            // per-expert epilogue: bias + relu + weighted accumulate (LDS-const only)
            int e = t >> 4;
            float b1v[4];
#pragma unroll
            for (int n = 0; n < 4; ++n)
                b1v[n] = b1Lds[e * 128 + wc * 64 + n * 16 + l15];
#pragma unroll
            for (int m = 0; m < 4; ++m)
#pragma unroll
                for (int j = 0; j < 4; ++j) {
                    int lrow = wr * 64 + m * 16 + kg * 4 + j;
                    float w = wmixLds[lrow * 8 + e];
#pragma unroll
                    for (int n = 0; n < 4; ++n) {
                        float h = fmaxf(acc[m][n][j] + b1v[n], 0.0f);
                        mix[m][n][j] += w * h;
                        acc[m][n][j] = 0.0f;
                    }
                }
        }
    }
#undef KB0
#undef KB1

    // final relu + store
#pragma unroll
    for (int m = 0; m < 4; ++m)
#pragma unroll
        for (int n = 0; n < 4; ++n)
#pragma unroll
            for (int j = 0; j < 4; ++j) {
                int lrow = wr * 64 + m * 16 + kg * 4 + j;
                int col = bn * 128 + wc * 64 + n * 16 + l15;
                mixed[(size_t)(bm * 128 + lrow) * 1024 + col] = fmaxf(mix[m][n][j], 0.0f);
            }
}

// ---------- head: q[b] = mixed[b,:] . Wh[c[b],:] + bh[c[b]] ----------
__global__ void k_head(const float* __restrict__ mixed, const float* __restrict__ Wh,
                       const float* __restrict__ bh, const int* __restrict__ c,
                       float* __restrict__ q, int Bc, int row0) {
    int row = blockIdx.x * 4 + (threadIdx.x >> 6);
    int lane = threadIdx.x & 63;
    if (row >= Bc) return;
    int grow = row0 + row;
    int ctx = c[grow];
    const float4* m4 = (const float4*)(mixed + (size_t)row * 1024);
    const float4* w4 = (const float4*)(Wh + (size_t)ctx * 1024);
    float s = 0.0f;
#pragma unroll
    for (int i = 0; i < 4; ++i) {
        float4 a = m4[lane + i * 64];
        float4 b = w4[lane + i * 64];
        s += a.x * b.x + a.y * b.y + a.z * b.z + a.w * b.w;
    }
#pragma unroll
    for (int off = 32; off > 0; off >>= 1) s += __shfl_down(s, off);
    if (lane == 0) q[grow] = s + bh[ctx];
}

// ---------- host ----------
extern "C" void kernel_launch(void* const* d_in, const int* in_sizes, int n_in,
                              void* d_out, int out_size, void* d_ws, size_t ws_size,
                              hipStream_t stream) {
    const float* state  = (const float*)d_in[0];
    const float* action = (const float*)d_in[1];
    const int*   c      = (const int*)d_in[2];
    const float* W0     = (const float*)d_in[3];
    const float* b0     = (const float*)d_in[4];
    const float* W1     = (const float*)d_in[5];
    const float* b1     = (const float*)d_in[6];
    const float* Wte    = (const float*)d_in[7];
    const float* Wh     = (const float*)d_in[8];
    const float* bh     = (const float*)d_in[9];
    float* q = (float*)d_out;
    int B = in_sizes[2];   // c has B elements

    // workspace layout
    char* p = (char*)d_ws;
    unsigned short* W1T = (unsigned short*)p; p += (size_t)8 * 1024 * 1024 * 2;  // 16 MB
    unsigned short* W0T = (unsigned short*)p; p += (size_t)8 * 1024 * 64 * 2;    // 1 MB
    unsigned short* SA  = (unsigned short*)p; p += (size_t)B * 64 * 2;
    float* wmix         = (float*)p;          p += (size_t)B * 8 * 4;
    size_t fixed = (size_t)(p - (char*)d_ws);

    int Bc = B;
    while (Bc > 256 && fixed + (size_t)Bc * (8 * 1024 * 2 + 1024 * 4) > ws_size) Bc >>= 1;

    unsigned short* H0 = (unsigned short*)p; p += (size_t)8 * Bc * 1024 * 2;
    float* mixed       = (float*)p;

    k_prep_sa<<<(B + 255) / 256, 256, 0, stream>>>(state, action, c, Wte, SA, wmix, B);
    k_prep_w0t<<<(8 * 1024) / 256, 256, 0, stream>>>(W0, W0T);
    k_prep_w1t<<<dim3(16, 16, 8), 256, 0, stream>>>(W1, W1T);

    for (int row0 = 0; row0 < B; row0 += Bc) {
        k_layer0<<<dim3(Bc / 128, 8, 8), 256, 0, stream>>>(SA, W0T, b0, H0, Bc, row0);
        k_layer1_mix<<<(Bc / 128) * 8, 256, 0, stream>>>(H0, W1T, b1, wmix, mixed, Bc, row0);
        k_head<<<(Bc + 3) / 4, 256, 0, stream>>>(mixed, Wh, bh, c, q, Bc, row0);
    }
}